// Round 1
// baseline (1354.890 us; speedup 1.0000x reference)
//
#include <hip/hip_runtime.h>
#include <hip/hip_bf16.h>

// HunyuanTopKGate: x[4096,4096] fp32, wg[64,4096] fp32 ->
//   combine_weights [T,E,C] fp32  ++  dispatch_mask [T,E,C] (as fp32 0/1)
// T=4096, E=64, K=8, C = out_size / (2*T*E)  (capacity = max expert load, so
// no token is ever dropped and C is recoverable from the output size).
//
// Pipeline:
//   0. hipMemsetAsync(d_out, 0)              -- 1.2 GB, the roofline pole
//   1. gemm_logits: fp64-accumulated logits  -- exact ordering vs np ref
//   2. topk_kernel: wave/token softmax+top8  -- fp32-gate compare, tie->low idx
//   3. rank_kernel: per-expert stable prefix count over k-major scan order
//   4. scatter_kernel: 32768 nonzero writes
//
// ws layout: logits (2 MB double) | idx_kt (128 KB) | rank_kt (128 KB) | w_kt (128 KB)

#define TOK 4096
#define HID 4096
#define NE  64
#define NK  8

// ---------------- 1. logits GEMM, fp64 accumulate ----------------
// 256 blocks x 256 thr; block = 16 tokens x 64 experts, BK=64.
// thread = (tok = tid&15) x (4 experts at (tid>>4)*4). acc in double.
__global__ __launch_bounds__(256) void gemm_logits(
    const float* __restrict__ x, const float* __restrict__ wg,
    double* __restrict__ logits) {
  __shared__ float xs[16][68];   // +4 pad keeps float4 alignment, breaks stride
  __shared__ float wsh[64][68];
  const int tid = threadIdx.x;
  const int t0  = blockIdx.x * 16;
  const int tok = tid & 15;
  const int eg  = tid >> 4;          // 0..15 -> experts eg*4..eg*4+3
  const int lrow = tid >> 4;         // load row 0..15
  const int lq   = tid & 15;         // load quad 0..15
  double acc[4] = {0.0, 0.0, 0.0, 0.0};

  for (int k0 = 0; k0 < HID; k0 += 64) {
    // stage x tile: 16 rows x 64 floats
    {
      float4 v = *(const float4*)&x[(size_t)(t0 + lrow) * HID + k0 + lq * 4];
      *(float4*)&xs[lrow][lq * 4] = v;
    }
    // stage w tile: 64 rows x 64 floats
#pragma unroll
    for (int it = 0; it < 4; ++it) {
      int r = it * 16 + lrow;
      float4 v = *(const float4*)&wg[(size_t)r * HID + k0 + lq * 4];
      *(float4*)&wsh[r][lq * 4] = v;
    }
    __syncthreads();
#pragma unroll
    for (int kk = 0; kk < 64; kk += 4) {
      float4 xv = *(const float4*)&xs[tok][kk];
#pragma unroll
      for (int j = 0; j < 4; ++j) {
        float4 wv = *(const float4*)&wsh[eg * 4 + j][kk];
        acc[j] = fma((double)xv.x, (double)wv.x, acc[j]);
        acc[j] = fma((double)xv.y, (double)wv.y, acc[j]);
        acc[j] = fma((double)xv.z, (double)wv.z, acc[j]);
        acc[j] = fma((double)xv.w, (double)wv.w, acc[j]);
      }
    }
    __syncthreads();
  }
#pragma unroll
  for (int j = 0; j < 4; ++j)
    logits[(size_t)(t0 + tok) * NE + eg * 4 + j] = acc[j];
}

// ---------------- 2. softmax + top-8 per token (one wave64/token) ----------
// Compare fp32-rounded gates (tie -> lower index) to mimic jax.lax.top_k on
// fp32 gates; gate values themselves kept in double.
__global__ __launch_bounds__(256) void topk_kernel(
    const double* __restrict__ logits,
    int* __restrict__ idx_kt, float* __restrict__ w_kt) {
  const int gid  = blockIdx.x * blockDim.x + threadIdx.x;
  const int t    = gid >> 6;
  const int lane = gid & 63;

  double v = logits[(size_t)t * NE + lane];
  // wave max
  double m = v;
#pragma unroll
  for (int off = 32; off; off >>= 1) {
    double o = __shfl_xor(m, off);
    m = o > m ? o : m;
  }
  double g = exp(v - m);
  double s = g;
#pragma unroll
  for (int off = 32; off; off >>= 1) s += __shfl_xor(s, off);
  double gate = g / s;

  float key = (float)gate;      // active selection key; gates > 0 always
  double ssel = 0.0;
  int my_k = -1;
#pragma unroll
  for (int k = 0; k < NK; ++k) {
    float bv = key;
    int   bi = lane;
#pragma unroll
    for (int off = 32; off; off >>= 1) {
      float ov = __shfl_xor(bv, off);
      int   oi = __shfl_xor(bi, off);
      if (ov > bv || (ov == bv && oi < bi)) { bv = ov; bi = oi; }
    }
    ssel += __shfl(gate, bi);
    if (lane == bi) { my_k = k; key = -1.0f; }
  }
  double gs = ssel;
  const double eps = (double)1.1920929e-07f;
  if (gs < eps) gs = eps;

  if (my_k >= 0) {
    idx_kt[my_k * TOK + t] = lane;
    w_kt [my_k * TOK + t] = (float)(gate / gs);
  }
}

// ---------------- 3. ranks: stable prefix count per expert --------------
// Scan order i = k*TOK + t (topk-major). One block per expert; ballot-based
// segmented count. rank(i) = # earlier scan entries with same expert.
__global__ __launch_bounds__(256) void rank_kernel(
    const int* __restrict__ idx_kt, int* __restrict__ rank_kt) {
  const int e    = blockIdx.x;
  const int tid  = threadIdx.x;
  const int lane = tid & 63;
  const int w    = tid >> 6;
  __shared__ int wt[4];
  int running = 0;                       // all threads keep identical copy
  const unsigned long long below = (1ull << lane) - 1ull;  // lane<64 safe

  for (int i0 = 0; i0 < NK * TOK; i0 += 256) {
    const int i = i0 + tid;
    const bool mhit = (idx_kt[i] == e);
    unsigned long long mask = __ballot(mhit);
    if (lane == 0) wt[w] = __popcll(mask);
    __syncthreads();
    int woff = 0, tot = 0;
#pragma unroll
    for (int j = 0; j < 4; ++j) {
      int c = wt[j];
      tot += c;
      if (j < w) woff += c;
    }
    if (mhit) rank_kt[i] = running + woff + __popcll(mask & below);
    running += tot;
    __syncthreads();
  }
}

// ---------------- 4. scatter the 32768 nonzeros ----------------
__global__ __launch_bounds__(256) void scatter_kernel(
    const int* __restrict__ idx_kt, const int* __restrict__ rank_kt,
    const float* __restrict__ w_kt, float* __restrict__ out, int C) {
  const int i = blockIdx.x * 256 + threadIdx.x;     // 0..32767, = k*TOK + t
  const int t = i & (TOK - 1);
  const int e = idx_kt[i];
  const int c = rank_kt[i];
  const float wv = w_kt[i];
  if (e >= 0 && e < NE && c >= 0 && c < C) {
    size_t off = ((size_t)t * NE + e) * (size_t)C + (size_t)c;
    out[off] = wv;                                  // combine_weights
    out[(size_t)TOK * NE * C + off] = 1.0f;         // dispatch_mask
  }
}

extern "C" void kernel_launch(void* const* d_in, const int* in_sizes, int n_in,
                              void* d_out, int out_size, void* d_ws, size_t ws_size,
                              hipStream_t stream) {
  const float* x  = (const float*)d_in[0];   // [4096,4096]
  const float* wg = (const float*)d_in[1];   // [64,4096]
  float* out = (float*)d_out;

  const int C = out_size / (2 * TOK * NE);   // capacity from output size

  char* ws = (char*)d_ws;
  double* logits = (double*)ws;                                   // 2 MB
  int*    idx_kt = (int*)  (ws + (size_t)2 * 1024 * 1024);        // 128 KB
  int*    rank_kt= (int*)  (ws + (size_t)2 * 1024 * 1024 + 131072);
  float*  w_kt   = (float*)(ws + (size_t)2 * 1024 * 1024 + 2 * 131072);

  // zero the whole output (poisoned with 0xAA before every timed launch)
  hipMemsetAsync(d_out, 0, (size_t)out_size * sizeof(float), stream);

  gemm_logits  <<<TOK / 16, 256, 0, stream>>>(x, wg, logits);
  topk_kernel  <<<TOK * 64 / 256, 256, 0, stream>>>(logits, idx_kt, w_kt);
  rank_kernel  <<<NE, 256, 0, stream>>>(idx_kt, rank_kt);
  scatter_kernel<<<NK * TOK / 256, 256, 0, stream>>>(idx_kt, rank_kt, w_kt, out, C);
}

// Round 3
// 1283.251 us; speedup vs baseline: 1.0558x; 1.0558x over previous
//
#include <hip/hip_runtime.h>
#include <hip/hip_bf16.h>

// HunyuanTopKGate: x[4096,4096] fp32, wg[64,4096] fp32 ->
//   combine_weights [T,E,C] fp32 ++ dispatch_mask [T,E,C] (as fp32 0/1)
// C = out_size/(2*T*E) = 2268 measured -> 4.76 GB output zero-fill (~755us
// at the 6.3 TB/s fill ceiling) is the roofline pole.
//
// Round 3: fp64 MFMA GEMM with RUNTIME-PROBED C/D layout (round 2 failed on
// an assumed layout). Probe: mfma(lane,1,0) -> D[m][n]=4m+96 everywhere,
// decode row per (lane,reg); mfma(1,lane,0) -> 4n+96, decode col. Works for
// any bijection. Insurance: sample-verify vs exact fp64 dots -> flag ->
// always-launched repair kernel (early-exit when flag clear) recomputes
// logits vector-fp64, guaranteeing correctness even if operand layouts
// surprise us.

#define TOK 4096
#define HID 4096
#define NE  64
#define NK  8

typedef double v4d __attribute__((ext_vector_type(4)));

// ---------------- 1. logits GEMM via fp64 MFMA ----------------
// Block: 256 thr = 4 waves; tile 64 tokens x 64 experts; K-chunk kchunk.
// Wave w: token rows w*16..w*16+15, 4 expert column tiles.
// A[m][k]: lane = m + 16k ; B[k][n]: lane = n + 16k (AMD blog layout).
// C/D: probed at runtime.
__global__ __launch_bounds__(256) void gemm_logits_mfma(
    const float* __restrict__ x, const float* __restrict__ wg,
    double* __restrict__ partial, int kchunk) {
  __shared__ float xs[64][68];    // stride 68 -> 2-way LDS aliasing (free)
  __shared__ float wsh[64][68];
  const int tid  = threadIdx.x;
  const int lane = tid & 63;
  const int w    = tid >> 6;
  const int m16  = lane & 15;
  const int q    = lane >> 4;
  const int t0   = blockIdx.x * 64;
  const int k0   = blockIdx.y * kchunk;

  // --- runtime C/D layout probe ---
  v4d pr = {0.0, 0.0, 0.0, 0.0};
  v4d pc = pr;
  pr = __builtin_amdgcn_mfma_f64_16x16x4f64((double)lane, 1.0, pr, 0, 0, 0);
  pc = __builtin_amdgcn_mfma_f64_16x16x4f64(1.0, (double)lane, pc, 0, 0, 0);
  int rmap[4], cmap[4];
#pragma unroll
  for (int v = 0; v < 4; ++v) {
    int rv = (((int)(pr[v] + 0.5)) - 96) >> 2;   // rowsum = 4m + 96
    int cv = (((int)(pc[v] + 0.5)) - 96) >> 2;   // colsum = 4n + 96
    rmap[v] = rv < 0 ? 0 : (rv > 15 ? 15 : rv);
    cmap[v] = cv < 0 ? 0 : (cv > 15 ? 15 : cv);
  }

  v4d acc0 = {0.0, 0.0, 0.0, 0.0};
  v4d acc1 = acc0, acc2 = acc0, acc3 = acc0;

  const int lrow = tid >> 2;          // 0..63: 4 threads per row
  const int lcol = (tid & 3) * 16;    // 16 floats (4 float4) per thread

  for (int s = 0; s < kchunk; s += 64) {
    const int kk0 = k0 + s;
#pragma unroll
    for (int j = 0; j < 4; ++j) {
      *(float4*)&xs [lrow][lcol + j * 4] =
          *(const float4*)&x [(size_t)(t0 + lrow) * HID + kk0 + lcol + j * 4];
      *(float4*)&wsh[lrow][lcol + j * 4] =
          *(const float4*)&wg[(size_t)lrow * HID + kk0 + lcol + j * 4];
    }
    __syncthreads();
#pragma unroll
    for (int s4 = 0; s4 < 16; ++s4) {
      const int kr = s4 * 4 + q;
      double a  = (double)xs [w * 16 + m16][kr];
      double b0 = (double)wsh[ 0 + m16][kr];
      double b1 = (double)wsh[16 + m16][kr];
      double b2 = (double)wsh[32 + m16][kr];
      double b3 = (double)wsh[48 + m16][kr];
      acc0 = __builtin_amdgcn_mfma_f64_16x16x4f64(a, b0, acc0, 0, 0, 0);
      acc1 = __builtin_amdgcn_mfma_f64_16x16x4f64(a, b1, acc1, 0, 0, 0);
      acc2 = __builtin_amdgcn_mfma_f64_16x16x4f64(a, b2, acc2, 0, 0, 0);
      acc3 = __builtin_amdgcn_mfma_f64_16x16x4f64(a, b3, acc3, 0, 0, 0);
    }
    __syncthreads();
  }

  double* base = partial + (size_t)blockIdx.y * TOK * NE;
#pragma unroll
  for (int v = 0; v < 4; ++v) {
    const int row = t0 + w * 16 + rmap[v];
    const int col = cmap[v];
    double* rp = base + (size_t)row * NE;
    rp[ 0 + col] = acc0[v];
    rp[16 + col] = acc1[v];
    rp[32 + col] = acc2[v];
    rp[48 + col] = acc3[v];
  }
}

// ---------------- 1b. verify: sample 512 logits vs exact fp64 dots --------
__global__ __launch_bounds__(256) void verify_kernel(
    const float* __restrict__ x, const float* __restrict__ wg,
    const double* __restrict__ partial, int nsplit, int* __restrict__ flag) {
  const int gid  = blockIdx.x * blockDim.x + threadIdx.x;
  const int wid  = gid >> 6;          // 0..511
  const int lane = gid & 63;
  const int t = (wid * 521) & (TOK - 1);  // odd stride: diverse row residues
  const int e = wid & 63;
  double acc = 0.0;
  for (int k = lane; k < HID; k += 64)
    acc = fma((double)x[(size_t)t * HID + k], (double)wg[(size_t)e * HID + k], acc);
#pragma unroll
  for (int off = 32; off; off >>= 1) acc += __shfl_xor(acc, off);
  if (lane == 0) {
    double got = 0.0;
    for (int p = 0; p < nsplit; ++p)
      got += partial[(size_t)p * TOK * NE + (size_t)t * NE + e];
    if (!(fabs(got - acc) <= 1e-6)) atomicOr(flag, 1);  // NaN-safe
  }
}

// ---------------- 1c. repair: full vector-fp64 recompute if flag set ------
__global__ __launch_bounds__(256) void repair_gemm(
    const float* __restrict__ x, const float* __restrict__ wg,
    double* __restrict__ partial, int nsplit, const int* __restrict__ flag) {
  if (*(volatile const int*)flag == 0) return;
  const int gid = blockIdx.x * 256 + threadIdx.x;   // 0..262143
  const int t = gid >> 6;
  const int e = gid & 63;
  double acc = 0.0;
  for (int k = 0; k < HID; ++k)
    acc = fma((double)x[(size_t)t * HID + k], (double)wg[(size_t)e * HID + k], acc);
  partial[(size_t)t * NE + e] = acc;
  for (int p = 1; p < nsplit; ++p)
    partial[(size_t)p * TOK * NE + (size_t)t * NE + e] = 0.0;
}

// ---------------- 2. softmax + top-8 per token (one wave64/token) ----------
__global__ __launch_bounds__(256) void topk_kernel(
    const double* __restrict__ partial, int nsplit,
    int* __restrict__ idx_kt, float* __restrict__ w_kt) {
  const int gid  = blockIdx.x * blockDim.x + threadIdx.x;
  const int t    = gid >> 6;
  const int lane = gid & 63;

  double v = 0.0;
  for (int p = 0; p < nsplit; ++p)
    v += partial[(size_t)p * TOK * NE + (size_t)t * NE + lane];

  double m = v;
#pragma unroll
  for (int off = 32; off; off >>= 1) {
    double o = __shfl_xor(m, off);
    m = o > m ? o : m;
  }
  double g = exp(v - m);
  double s = g;
#pragma unroll
  for (int off = 32; off; off >>= 1) s += __shfl_xor(s, off);
  double gate = g / s;

  float key = (float)gate;    // fp32-rounded selection key, tie -> lower idx
  double ssel = 0.0;
  int my_k = -1;
#pragma unroll
  for (int k = 0; k < NK; ++k) {
    float bv = key;
    int   bi = lane;
#pragma unroll
    for (int off = 32; off; off >>= 1) {
      float ov = __shfl_xor(bv, off);
      int   oi = __shfl_xor(bi, off);
      if (ov > bv || (ov == bv && oi < bi)) { bv = ov; bi = oi; }
    }
    ssel += __shfl(gate, bi);
    if (lane == bi) { my_k = k; key = -1.0f; }
  }
  double gs = ssel;
  const double eps = (double)1.1920929e-07f;
  if (gs < eps) gs = eps;

  if (my_k >= 0) {
    idx_kt[my_k * TOK + t] = lane;
    w_kt [my_k * TOK + t] = (float)(gate / gs);
  }
}

// ---------------- 3. ranks: stable prefix count per expert --------------
__global__ __launch_bounds__(256) void rank_kernel(
    const int* __restrict__ idx_kt, int* __restrict__ rank_kt) {
  const int e    = blockIdx.x;
  const int tid  = threadIdx.x;
  const int lane = tid & 63;
  const int w    = tid >> 6;
  __shared__ int wt[4];
  int running = 0;
  const unsigned long long below = (1ull << lane) - 1ull;

  for (int i0 = 0; i0 < NK * TOK; i0 += 256) {
    const int i = i0 + tid;
    const bool mhit = (idx_kt[i] == e);
    unsigned long long mask = __ballot(mhit);
    if (lane == 0) wt[w] = __popcll(mask);
    __syncthreads();
    int woff = 0, tot = 0;
#pragma unroll
    for (int j = 0; j < 4; ++j) {
      int c = wt[j];
      tot += c;
      if (j < w) woff += c;
    }
    if (mhit) rank_kt[i] = running + woff + __popcll(mask & below);
    running += tot;
    __syncthreads();
  }
}

// ---------------- 4. scatter the 32768 nonzeros ----------------
__global__ __launch_bounds__(256) void scatter_kernel(
    const int* __restrict__ idx_kt, const int* __restrict__ rank_kt,
    const float* __restrict__ w_kt, float* __restrict__ out, int C) {
  const int i = blockIdx.x * 256 + threadIdx.x;   // 0..32767, = k*TOK + t
  const int t = i & (TOK - 1);
  const int e = idx_kt[i];
  const int c = rank_kt[i];
  const float wv = w_kt[i];
  if (e >= 0 && e < NE && c >= 0 && c < C) {
    size_t off = ((size_t)t * NE + e) * (size_t)C + (size_t)c;
    out[off] = wv;                                // combine_weights
    out[(size_t)TOK * NE * C + off] = 1.0f;       // dispatch_mask
  }
}

extern "C" void kernel_launch(void* const* d_in, const int* in_sizes, int n_in,
                              void* d_out, int out_size, void* d_ws, size_t ws_size,
                              hipStream_t stream) {
  const float* x  = (const float*)d_in[0];   // [4096,4096]
  const float* wg = (const float*)d_in[1];   // [64,4096]
  float* out = (float*)d_out;

  const int C = out_size / (2 * TOK * NE);   // capacity from output size

  const size_t slab = (size_t)TOK * NE * sizeof(double);   // 2 MB per partial
  const size_t tail = 3 * (size_t)NK * TOK * sizeof(int);  // idx+rank+w
  int nsplit = 8;
  while (nsplit > 1 && (size_t)nsplit * slab + tail + 64 > ws_size) nsplit >>= 1;
  const int kchunk = HID / nsplit;

  char* ws = (char*)d_ws;
  double* partial = (double*)ws;
  int*    idx_kt  = (int*)  (ws + (size_t)nsplit * slab);
  int*    rank_kt = (int*)  (ws + (size_t)nsplit * slab + (size_t)NK * TOK * 4);
  float*  w_kt    = (float*)(ws + (size_t)nsplit * slab + (size_t)NK * TOK * 8);
  int*    flag    = (int*)  (ws + (size_t)nsplit * slab + tail);

  // zero output (poisoned 0xAA before every timed launch) + the verify flag
  hipMemsetAsync(d_out, 0, (size_t)out_size * sizeof(float), stream);
  hipMemsetAsync(flag, 0, sizeof(int), stream);

  dim3 ggrid(TOK / 64, nsplit);
  gemm_logits_mfma<<<ggrid, 256, 0, stream>>>(x, wg, partial, kchunk);
  verify_kernel   <<<128, 256, 0, stream>>>(x, wg, partial, nsplit, flag);
  repair_gemm     <<<TOK * NE / 256, 256, 0, stream>>>(x, wg, partial, nsplit, flag);
  topk_kernel     <<<TOK * 64 / 256, 256, 0, stream>>>(partial, nsplit, idx_kt, w_kt);
  rank_kernel     <<<NE, 256, 0, stream>>>(idx_kt, rank_kt);
  scatter_kernel  <<<NK * TOK / 256, 256, 0, stream>>>(idx_kt, rank_kt, w_kt, out, C);
}

// Round 5
// 1263.948 us; speedup vs baseline: 1.0720x; 1.0153x over previous
//
#include <hip/hip_runtime.h>
#include <hip/hip_bf16.h>

// HunyuanTopKGate: x[4096,4096] fp32, wg[64,4096] fp32 ->
//   combine_weights [T,E,C] fp32 ++ dispatch_mask [T,E,C] (as fp32 0/1)
// C = out_size/(2*T*E) = 2268 measured -> 4.76 GB output zero-fill (~765us
// at the 6.3 TB/s fill ceiling) is the roofline pole.
//
// Round 4 (resubmit; round-4 bench hit GPUAcquisitionTimeout, never ran):
// round 3's C/D probe assumed A's operand layout (m=lane&15) -- if f64 MFMA
// is k-inner (m=lane>>2,k=lane&3) both staging and decode were wrong and
// repair ran (+410us, matches observed 518us tail). Now the probe first
// detects the layout FAMILY via rowsum residues (k-outer rowsum=4m+96
// === 0 mod 4; k-inner 16m+6 === 2 mod 4), then picks staging indices and
// the C/D decode accordingly. verify+repair insurance retained.

#define TOK 4096
#define HID 4096
#define NE  64
#define NK  8

typedef double v4d __attribute__((ext_vector_type(4)));

// ---------------- 1. logits GEMM via fp64 MFMA ----------------
// Block: 256 thr = 4 waves; tile 64 tokens x 64 experts; K-chunk kchunk.
// Wave w: token rows w*16..w*16+15, 4 expert col tiles. Operand + C/D
// layouts detected at runtime (see header comment).
__global__ __launch_bounds__(256) void gemm_logits_mfma(
    const float* __restrict__ x, const float* __restrict__ wg,
    double* __restrict__ partial, int kchunk, int* __restrict__ flag) {
  __shared__ float xs[64][68];    // stride 68: 2-way LDS aliasing (free)
  __shared__ float wsh[64][68];
  const int tid  = threadIdx.x;
  const int lane = tid & 63;
  const int w    = tid >> 6;
  const int t0   = blockIdx.x * 64;
  const int k0   = blockIdx.y * kchunk;

  // clear the verify flag (gemm grid completes before verify launches)
  if (blockIdx.x == 0 && blockIdx.y == 0 && tid == 0) *flag = 0;

  // --- runtime layout probe ---
  v4d z = {0.0, 0.0, 0.0, 0.0};
  v4d pr = __builtin_amdgcn_mfma_f64_16x16x4f64((double)lane, 1.0, z, 0, 0, 0);
  v4d pc = __builtin_amdgcn_mfma_f64_16x16x4f64(1.0, (double)lane, z, 0, 0, 0);
  const int pv0 = (int)(pr[0] + 0.5);
  const int qv0 = (int)(pc[0] + 0.5);
  const bool a_kouter = ((pv0 & 3) == 0);   // rowsum family of A
  const bool b_kouter = ((qv0 & 3) == 0);   // colsum family of B
  const int am = a_kouter ? (lane & 15) : (lane >> 2);
  const int ak = a_kouter ? (lane >> 4) : (lane & 3);
  const int bn = b_kouter ? (lane & 15) : (lane >> 2);
  const int bk = b_kouter ? (lane >> 4) : (lane & 3);
  int rmap[4], cmap[4];
#pragma unroll
  for (int v = 0; v < 4; ++v) {
    int V = (int)(pr[v] + 0.5);
    int rv = a_kouter ? ((V - 96) >> 2) : ((V - 6) >> 4);
    rmap[v] = rv < 0 ? 0 : (rv > 15 ? 15 : rv);
    int W = (int)(pc[v] + 0.5);
    int cv = b_kouter ? ((W - 96) >> 2) : ((W - 6) >> 4);
    cmap[v] = cv < 0 ? 0 : (cv > 15 ? 15 : cv);
  }

  v4d acc0 = {0.0, 0.0, 0.0, 0.0};
  v4d acc1 = acc0, acc2 = acc0, acc3 = acc0;

  const int lrow = tid >> 2;          // 0..63: 4 threads per row
  const int lcol = (tid & 3) * 16;    // 16 floats (4 float4) per thread

  for (int s = 0; s < kchunk; s += 64) {
    const int kk0 = k0 + s;
#pragma unroll
    for (int j = 0; j < 4; ++j) {
      *(float4*)&xs [lrow][lcol + j * 4] =
          *(const float4*)&x [(size_t)(t0 + lrow) * HID + kk0 + lcol + j * 4];
      *(float4*)&wsh[lrow][lcol + j * 4] =
          *(const float4*)&wg[(size_t)lrow * HID + kk0 + lcol + j * 4];
    }
    __syncthreads();
#pragma unroll
    for (int s4 = 0; s4 < 16; ++s4) {
      double a  = (double)xs [w * 16 + am][s4 * 4 + ak];
      double b0 = (double)wsh[ 0 + bn][s4 * 4 + bk];
      double b1 = (double)wsh[16 + bn][s4 * 4 + bk];
      double b2 = (double)wsh[32 + bn][s4 * 4 + bk];
      double b3 = (double)wsh[48 + bn][s4 * 4 + bk];
      acc0 = __builtin_amdgcn_mfma_f64_16x16x4f64(a, b0, acc0, 0, 0, 0);
      acc1 = __builtin_amdgcn_mfma_f64_16x16x4f64(a, b1, acc1, 0, 0, 0);
      acc2 = __builtin_amdgcn_mfma_f64_16x16x4f64(a, b2, acc2, 0, 0, 0);
      acc3 = __builtin_amdgcn_mfma_f64_16x16x4f64(a, b3, acc3, 0, 0, 0);
    }
    __syncthreads();
  }

  double* base = partial + (size_t)blockIdx.y * TOK * NE;
#pragma unroll
  for (int v = 0; v < 4; ++v) {
    const int row = t0 + w * 16 + rmap[v];
    const int col = cmap[v];
    double* rp = base + (size_t)row * NE;
    rp[ 0 + col] = acc0[v];
    rp[16 + col] = acc1[v];
    rp[32 + col] = acc2[v];
    rp[48 + col] = acc3[v];
  }
}

// ---------------- 1b. verify: sample 512 logits vs exact fp64 dots --------
__global__ __launch_bounds__(256) void verify_kernel(
    const float* __restrict__ x, const float* __restrict__ wg,
    const double* __restrict__ partial, int nsplit, int* __restrict__ flag) {
  const int gid  = blockIdx.x * blockDim.x + threadIdx.x;
  const int wid  = gid >> 6;          // 0..511
  const int lane = gid & 63;
  const int t = (wid * 521) & (TOK - 1);
  const int e = wid & 63;
  double acc = 0.0;
  for (int k = lane; k < HID; k += 64)
    acc = fma((double)x[(size_t)t * HID + k], (double)wg[(size_t)e * HID + k], acc);
#pragma unroll
  for (int off = 32; off; off >>= 1) acc += __shfl_xor(acc, off);
  if (lane == 0) {
    double got = 0.0;
    for (int p = 0; p < nsplit; ++p)
      got += partial[(size_t)p * TOK * NE + (size_t)t * NE + e];
    if (!(fabs(got - acc) <= 1e-6)) atomicOr(flag, 1);  // NaN-safe
  }
}

// ---------------- 1c. repair: full vector-fp64 recompute if flag set ------
__global__ __launch_bounds__(256) void repair_gemm(
    const float* __restrict__ x, const float* __restrict__ wg,
    double* __restrict__ partial, int nsplit, const int* __restrict__ flag) {
  if (*(volatile const int*)flag == 0) return;
  const int gid = blockIdx.x * 256 + threadIdx.x;   // 0..262143
  const int t = gid >> 6;
  const int e = gid & 63;
  double acc = 0.0;
  for (int k = 0; k < HID; ++k)
    acc = fma((double)x[(size_t)t * HID + k], (double)wg[(size_t)e * HID + k], acc);
  partial[(size_t)t * NE + e] = acc;
  for (int p = 1; p < nsplit; ++p)
    partial[(size_t)p * TOK * NE + (size_t)t * NE + e] = 0.0;
}

// ---------------- 2. softmax + top-8 per token (one wave64/token) ----------
__global__ __launch_bounds__(256) void topk_kernel(
    const double* __restrict__ partial, int nsplit,
    int* __restrict__ idx_kt, float* __restrict__ w_kt) {
  const int gid  = blockIdx.x * blockDim.x + threadIdx.x;
  const int t    = gid >> 6;
  const int lane = gid & 63;

  double v = 0.0;
  for (int p = 0; p < nsplit; ++p)
    v += partial[(size_t)p * TOK * NE + (size_t)t * NE + lane];

  double m = v;
#pragma unroll
  for (int off = 32; off; off >>= 1) {
    double o = __shfl_xor(m, off);
    m = o > m ? o : m;
  }
  double g = exp(v - m);
  double s = g;
#pragma unroll
  for (int off = 32; off; off >>= 1) s += __shfl_xor(s, off);
  double gate = g / s;

  float key = (float)gate;    // fp32-rounded selection key, tie -> lower idx
  double ssel = 0.0;
  int my_k = -1;
#pragma unroll
  for (int k = 0; k < NK; ++k) {
    float bv = key;
    int   bi = lane;
#pragma unroll
    for (int off = 32; off; off >>= 1) {
      float ov = __shfl_xor(bv, off);
      int   oi = __shfl_xor(bi, off);
      if (ov > bv || (ov == bv && oi < bi)) { bv = ov; bi = oi; }
    }
    ssel += __shfl(gate, bi);
    if (lane == bi) { my_k = k; key = -1.0f; }
  }
  double gs = ssel;
  const double eps = (double)1.1920929e-07f;
  if (gs < eps) gs = eps;

  if (my_k >= 0) {
    idx_kt[my_k * TOK + t] = lane;
    w_kt [my_k * TOK + t] = (float)(gate / gs);
  }
}

// ---------------- 3. ranks: stable prefix count per expert --------------
// 1024 threads/block (16 waves): 32 iterations over the 32768-entry scan.
__global__ __launch_bounds__(1024) void rank_kernel(
    const int* __restrict__ idx_kt, int* __restrict__ rank_kt) {
  const int e    = blockIdx.x;
  const int tid  = threadIdx.x;
  const int lane = tid & 63;
  const int w    = tid >> 6;          // 0..15
  __shared__ int wt[16];
  int running = 0;
  const unsigned long long below = (1ull << lane) - 1ull;

  for (int i0 = 0; i0 < NK * TOK; i0 += 1024) {
    const int i = i0 + tid;
    const bool mhit = (idx_kt[i] == e);
    unsigned long long mask = __ballot(mhit);
    if (lane == 0) wt[w] = __popcll(mask);
    __syncthreads();
    int woff = 0, tot = 0;
#pragma unroll
    for (int j = 0; j < 16; ++j) {
      int c = wt[j];
      tot += c;
      if (j < w) woff += c;
    }
    if (mhit) rank_kt[i] = running + woff + __popcll(mask & below);
    running += tot;
    __syncthreads();
  }
}

// ---------------- 4. scatter the 32768 nonzeros ----------------
__global__ __launch_bounds__(256) void scatter_kernel(
    const int* __restrict__ idx_kt, const int* __restrict__ rank_kt,
    const float* __restrict__ w_kt, float* __restrict__ out, int C) {
  const int i = blockIdx.x * 256 + threadIdx.x;   // 0..32767, = k*TOK + t
  const int t = i & (TOK - 1);
  const int e = idx_kt[i];
  const int c = rank_kt[i];
  const float wv = w_kt[i];
  if (e >= 0 && e < NE && c >= 0 && c < C) {
    size_t off = ((size_t)t * NE + e) * (size_t)C + (size_t)c;
    out[off] = wv;                                // combine_weights
    out[(size_t)TOK * NE * C + off] = 1.0f;       // dispatch_mask
  }
}

extern "C" void kernel_launch(void* const* d_in, const int* in_sizes, int n_in,
                              void* d_out, int out_size, void* d_ws, size_t ws_size,
                              hipStream_t stream) {
  const float* x  = (const float*)d_in[0];   // [4096,4096]
  const float* wg = (const float*)d_in[1];   // [64,4096]
  float* out = (float*)d_out;

  const int C = out_size / (2 * TOK * NE);   // capacity from output size

  const size_t slab = (size_t)TOK * NE * sizeof(double);   // 2 MB per partial
  const size_t tail = 3 * (size_t)NK * TOK * sizeof(int);  // idx+rank+w
  int nsplit = 8;
  while (nsplit > 1 && (size_t)nsplit * slab + tail + 64 > ws_size) nsplit >>= 1;
  const int kchunk = HID / nsplit;

  char* ws = (char*)d_ws;
  double* partial = (double*)ws;
  int*    idx_kt  = (int*)  (ws + (size_t)nsplit * slab);
  int*    rank_kt = (int*)  (ws + (size_t)nsplit * slab + (size_t)NK * TOK * 4);
  float*  w_kt    = (float*)(ws + (size_t)nsplit * slab + (size_t)NK * TOK * 8);
  int*    flag    = (int*)  (ws + (size_t)nsplit * slab + tail);

  // zero output (poisoned 0xAA before every timed launch)
  hipMemsetAsync(d_out, 0, (size_t)out_size * sizeof(float), stream);

  dim3 ggrid(TOK / 64, nsplit);
  gemm_logits_mfma<<<ggrid, 256, 0, stream>>>(x, wg, partial, kchunk, flag);
  verify_kernel   <<<128, 256, 0, stream>>>(x, wg, partial, nsplit, flag);
  repair_gemm     <<<TOK * NE / 256, 256, 0, stream>>>(x, wg, partial, nsplit, flag);
  topk_kernel     <<<TOK * 64 / 256, 256, 0, stream>>>(partial, nsplit, idx_kt, w_kt);
  rank_kernel     <<<NE, 1024, 0, stream>>>(idx_kt, rank_kt);
  scatter_kernel  <<<NK * TOK / 256, 256, 0, stream>>>(idx_kt, rank_kt, w_kt, out, C);
}